// Round 6
// baseline (201.912 us; speedup 1.0000x reference)
//
#include <hip/hip_runtime.h>

#define BB   8
#define CC   256
#define HWN  16384        // 128*128
#define PP   30
#define KD   128
#define GG   5
// d_out float offsets
#define OFF_Q   (33554432u)             // 8*256*128*128
#define OFF_SIM (OFF_Q + 30720u)        // + 30*8*128

// ---- kernel 1: fused q-projection + AT/c0 build (tiny; 240 blocks) ---------
// q[p,b,k] = Wq[p/G,k,:] . proto[p,b,:] + bq[p/G,k]
// AT[b,c,p] = sum_k q[p,b,k]*Wk[k,c]  (transposed so rows are p-contiguous)
// c0[b,p]   = sum_k q[p,b,k]*bk[k]
__global__ __launch_bounds__(256) void proj_kernel(
    const float* __restrict__ proto,  // [P,B,C]
    const float* __restrict__ Wq,     // [6,128,C]
    const float* __restrict__ bq,     // [6,128]
    const float* __restrict__ Wk,     // [128,C]
    const float* __restrict__ bk,     // [128]
    float* __restrict__ qout,         // [P,B,128] (into d_out)
    float* __restrict__ AT,           // [B,C,P]   (ws)
    float* __restrict__ c0)           // [B,P]     (ws)
{
    const int pb = blockIdx.x;        // p*B + b
    const int p = pb / BB, b = pb % BB, g = p / GG;
    const int tid = threadIdx.x;

    __shared__ float ps[CC];
    __shared__ float qs[KD];

    for (int c = tid; c < CC; c += 256) ps[c] = proto[pb * CC + c];
    __syncthreads();

    if (tid < KD) {
        const float* wrow = Wq + (size_t)(g * KD + tid) * CC;
        float a = 0.f;
        #pragma unroll 4
        for (int c = 0; c < CC; ++c) a += ps[c] * wrow[c];
        a += bq[g * KD + tid];
        qout[pb * KD + tid] = a;
        qs[tid] = a;
    }
    __syncthreads();

    float a = 0.f;
    #pragma unroll 4
    for (int k = 0; k < KD; ++k) a += qs[k] * Wk[k * CC + tid];
    AT[((size_t)b * CC + tid) * PP + p] = a;

    if (tid == 0) {
        float s = 0.f;
        for (int k = 0; k < KD; ++k) s += qs[k] * bk[k];
        c0[b * PP + p] = s;
    }
}

// ---- kernel 2: fused sim + softmax-max + weighted output -------------------
// 1 position/thread. Block = 64 positions x 4 waves; wave q owns channel
// quarter q. A rows are wave-uniform loads (s_load -> SGPR operand of v_fmac).
// Symmetric 2-stage cross-wave reduce; waves 0 & 2 both end with full sums
// (wave0 -> softmax weight, wave2 -> sim stores).
__global__ __launch_bounds__(256, 8) void fused_kernel(
    const float* __restrict__ X,    // [B,C,HW]
    const float* __restrict__ AT,   // [B,C,P]
    const float* __restrict__ c0,   // [B,P]
    float* __restrict__ out0,       // [B,C,HW]
    float* __restrict__ sim)        // [B,P,HW]
{
    const int b    = blockIdx.y;
    const int tid  = threadIdx.x;
    const int lane = tid & 63;
    const int q    = tid >> 6;
    const int n    = blockIdx.x * 64 + lane;

    __shared__ float buf0[PP][64];   // lane-major: conflict-free
    __shared__ float buf1[PP][64];
    __shared__ float wbuf[64];
    __shared__ float c0s[PP];

    if (tid < PP) c0s[tid] = c0[b * PP + tid];

    float acc[PP];
    #pragma unroll
    for (int p = 0; p < PP; ++p) acc[p] = 0.f;

    const float* xb  = X  + (size_t)b * CC * HWN + n;
    const float* atb = AT + (size_t)b * CC * PP;

    #pragma unroll 2
    for (int i = 0; i < 64; ++i) {
        const int ch = q * 64 + i;
        const float x = xb[(size_t)ch * HWN];
        const float* arow = atb + ch * PP;      // uniform address -> s_load
        #pragma unroll
        for (int p = 0; p < PP; ++p) acc[p] += arow[p] * x;
    }

    // stage 1: odd waves park their partials
    if (q == 1) {
        #pragma unroll
        for (int p = 0; p < PP; ++p) buf0[p][lane] = acc[p];
    }
    if (q == 3) {
        #pragma unroll
        for (int p = 0; p < PP; ++p) buf1[p][lane] = acc[p];
    }
    __syncthreads();

    // stage 2: waves 0,2 fold in and publish half-sums
    if (q == 0) {
        #pragma unroll
        for (int p = 0; p < PP; ++p) {
            acc[p] += buf0[p][lane];
            buf0[p][lane] = acc[p];
        }
    }
    if (q == 2) {
        #pragma unroll
        for (int p = 0; p < PP; ++p) {
            acc[p] += buf1[p][lane];
            buf1[p][lane] = acc[p];
        }
    }
    __syncthreads();

    // stage 3: waves 0,2 both have the full sum
    if (q == 0) {
        float m = -1e30f;
        #pragma unroll
        for (int p = 0; p < PP; ++p) {
            acc[p] += buf1[p][lane] + c0s[p];
            m = fmaxf(m, acc[p]);
        }
        float s = 0.f;
        #pragma unroll
        for (int p = 0; p < PP; ++p) s += __expf((acc[p] - m) * (1.f / 6.f));
        wbuf[lane] = 1.f / s;            // max_p softmax == 1/sum exp
    }
    if (q == 2) {
        #pragma unroll
        for (int p = 0; p < PP; ++p) {
            acc[p] += buf0[p][lane] + c0s[p];
            __builtin_nontemporal_store(acc[p],
                sim + ((size_t)b * PP + p) * HWN + n);
        }
    }
    __syncthreads();

    const float w = wbuf[lane];
    float* ob = out0 + (size_t)b * CC * HWN + n;
    #pragma unroll 8
    for (int i = 0; i < 64; ++i) {
        const size_t off = (size_t)(q * 64 + i) * HWN;
        const float x = __builtin_nontemporal_load(xb + off);
        __builtin_nontemporal_store(x * w, ob + off);
    }
}

extern "C" void kernel_launch(void* const* d_in, const int* in_sizes, int n_in,
                              void* d_out, int out_size, void* d_ws, size_t ws_size,
                              hipStream_t stream) {
    const float* X     = (const float*)d_in[0];
    const float* proto = (const float*)d_in[1];
    const float* Wk    = (const float*)d_in[2];
    const float* bk    = (const float*)d_in[3];
    const float* Wq    = (const float*)d_in[4];
    const float* bq    = (const float*)d_in[5];

    float* out  = (float*)d_out;
    float* qout = out + OFF_Q;
    float* sim  = out + OFF_SIM;

    float* AT = (float*)d_ws;              // 8*256*30 = 61440 floats
    float* c0 = AT + BB * CC * PP;         // 240 floats

    proj_kernel<<<PP * BB, 256, 0, stream>>>(proto, Wq, bq, Wk, bk, qout, AT, c0);

    dim3 grid(HWN / 64, BB);               // 256 x 8 = 2048 blocks
    fused_kernel<<<grid, 256, 0, stream>>>(X, AT, c0, out, sim);
}

// Round 7
// 97.040 us; speedup vs baseline: 2.0807x; 2.0807x over previous
//
#include <hip/hip_runtime.h>

#define BB   8
#define CC   256
#define HWN  16384        // 128*128
#define PP   30
#define KD   128
#define GG   5
// d_out float offsets
#define OFF_Q   (33554432u)             // 8*256*128*128
#define OFF_SIM (OFF_Q + 30720u)        // + 30*8*128

typedef float f32x2 __attribute__((ext_vector_type(2)));

// ---- kernel 1: fused q-projection + A/c0 build (tiny; 240 blocks) ----------
__global__ __launch_bounds__(256) void proj_kernel(
    const float* __restrict__ proto,  // [P,B,C]
    const float* __restrict__ Wq,     // [6,128,C]
    const float* __restrict__ bq,     // [6,128]
    const float* __restrict__ Wk,     // [128,C]
    const float* __restrict__ bk,     // [128]
    float* __restrict__ qout,         // [P,B,128] (into d_out)
    float* __restrict__ A,            // [B,P,C]   (ws)
    float* __restrict__ c0)           // [B,P]     (ws)
{
    const int pb = blockIdx.x;        // p*B + b
    const int p = pb / BB, b = pb % BB, g = p / GG;
    const int tid = threadIdx.x;

    __shared__ float ps[CC];
    __shared__ float qs[KD];

    for (int c = tid; c < CC; c += 256) ps[c] = proto[pb * CC + c];
    __syncthreads();

    if (tid < KD) {
        const float* wrow = Wq + (size_t)(g * KD + tid) * CC;
        float a = 0.f;
        #pragma unroll 4
        for (int c = 0; c < CC; ++c) a += ps[c] * wrow[c];
        a += bq[g * KD + tid];
        qout[pb * KD + tid] = a;
        qs[tid] = a;
    }
    __syncthreads();

    float a = 0.f;
    #pragma unroll 4
    for (int k = 0; k < KD; ++k) a += qs[k] * Wk[k * CC + tid];
    A[(size_t)(b * PP + p) * CC + tid] = a;

    if (tid == 0) {
        float s = 0.f;
        for (int k = 0; k < KD; ++k) s += qs[k] * bk[k];
        c0[b * PP + p] = s;
    }
}

// ---- kernel 2: fused sim + softmax-max + weighted output -------------------
// 2 positions/thread (float2). Block = 128 positions x 4 waves; wave q owns
// channel quarter q. A broadcast via v_readlane (lane l holds ch q*64+l).
// Chunked cross-wave reduce: wave0 finalizes pos j=0, wave2 finalizes j=1.
__global__ __launch_bounds__(256, 4) void fused_kernel(
    const float* __restrict__ X,    // [B,C,HW]
    const float* __restrict__ A,    // [B,P,C]
    const float* __restrict__ c0,   // [B,P]
    float* __restrict__ out0,       // [B,C,HW]
    float* __restrict__ sim)        // [B,P,HW]
{
    const int b    = blockIdx.y;
    const int tid  = threadIdx.x;
    const int lane = tid & 63;
    const int q    = tid >> 6;
    const int n0   = blockIdx.x * 128 + lane * 2;

    __shared__ float red[3][64][31];   // stride 31 -> conflict-free (23.8 KB)
    __shared__ float wbuf[64][2];
    __shared__ float c0s[PP];

    if (tid < PP) c0s[tid] = c0[b * PP + tid];

    // lane l holds A[b][p][q*64+l]
    float a[PP];
    #pragma unroll
    for (int p = 0; p < PP; ++p)
        a[p] = A[(size_t)(b * PP + p) * CC + q * 64 + lane];

    float acc0[PP], acc1[PP];
    #pragma unroll
    for (int p = 0; p < PP; ++p) { acc0[p] = 0.f; acc1[p] = 0.f; }

    const float* xb = X + (size_t)b * CC * HWN + n0;

    for (int i = 0; i < 64; i += 4) {          // 16 batches of 4 channels
        f32x2 xv[4];
        #pragma unroll
        for (int u = 0; u < 4; ++u)
            xv[u] = *(const f32x2*)(xb + (size_t)(q * 64 + i + u) * HWN);
        #pragma unroll
        for (int u = 0; u < 4; ++u) {
            const int ch = i + u;              // compile-time lane index
            #pragma unroll
            for (int p = 0; p < PP; ++p) {
                const float av = __int_as_float(
                    __builtin_amdgcn_readlane(__float_as_int(a[p]), ch));
                acc0[p] += av * xv[u].x;
                acc1[p] += av * xv[u].y;
            }
        }
    }
    __syncthreads();                           // also publishes c0s

    // ---- position j=0: waves 1,2,3 park; wave 0 folds ----
    if (q != 0) {
        #pragma unroll
        for (int p = 0; p < PP; ++p) red[q - 1][lane][p] = acc0[p];
    }
    __syncthreads();
    if (q == 0) {
        #pragma unroll
        for (int k = 0; k < 3; ++k)
            #pragma unroll
            for (int p = 0; p < PP; ++p) acc0[p] += red[k][lane][p];
        float m = -1e30f;
        #pragma unroll
        for (int p = 0; p < PP; ++p) {
            acc0[p] += c0s[p];
            m = fmaxf(m, acc0[p]);
            __builtin_nontemporal_store(acc0[p],
                sim + ((size_t)b * PP + p) * HWN + n0);
        }
        float s = 0.f;
        #pragma unroll
        for (int p = 0; p < PP; ++p) s += __expf((acc0[p] - m) * (1.f / 6.f));
        wbuf[lane][0] = 1.f / s;               // max_p softmax == 1/sum exp
    }
    __syncthreads();

    // ---- position j=1: waves 0,1,3 park; wave 2 folds ----
    if (q != 2) {
        const int slot = (q == 3) ? 2 : q;     // q in {0,1,3} -> {0,1,2}
        #pragma unroll
        for (int p = 0; p < PP; ++p) red[slot][lane][p] = acc1[p];
    }
    __syncthreads();
    if (q == 2) {
        #pragma unroll
        for (int k = 0; k < 3; ++k)
            #pragma unroll
            for (int p = 0; p < PP; ++p) acc1[p] += red[k][lane][p];
        float m = -1e30f;
        #pragma unroll
        for (int p = 0; p < PP; ++p) {
            acc1[p] += c0s[p];
            m = fmaxf(m, acc1[p]);
            __builtin_nontemporal_store(acc1[p],
                sim + ((size_t)b * PP + p) * HWN + n0 + 1);
        }
        float s = 0.f;
        #pragma unroll
        for (int p = 0; p < PP; ++p) s += __expf((acc1[p] - m) * (1.f / 6.f));
        wbuf[lane][1] = 1.f / s;
    }
    __syncthreads();

    f32x2 wv;
    wv.x = wbuf[lane][0];
    wv.y = wbuf[lane][1];
    float* ob = out0 + (size_t)b * CC * HWN + n0;
    #pragma unroll 8
    for (int i = 0; i < 64; ++i) {
        const size_t off = (size_t)(q * 64 + i) * HWN;
        f32x2 x = __builtin_nontemporal_load((const f32x2*)(xb + off));
        f32x2 o = x * wv;
        __builtin_nontemporal_store(o, (f32x2*)(ob + off));
    }
}

extern "C" void kernel_launch(void* const* d_in, const int* in_sizes, int n_in,
                              void* d_out, int out_size, void* d_ws, size_t ws_size,
                              hipStream_t stream) {
    const float* X     = (const float*)d_in[0];
    const float* proto = (const float*)d_in[1];
    const float* Wk    = (const float*)d_in[2];
    const float* bk    = (const float*)d_in[3];
    const float* Wq    = (const float*)d_in[4];
    const float* bq    = (const float*)d_in[5];

    float* out  = (float*)d_out;
    float* qout = out + OFF_Q;
    float* sim  = out + OFF_SIM;

    float* A  = (float*)d_ws;              // 61440 floats
    float* c0 = A + BB * PP * CC;          // 240 floats

    proj_kernel<<<PP * BB, 256, 0, stream>>>(proto, Wq, bq, Wk, bk, qout, A, c0);

    dim3 grid(HWN / 128, BB);              // 128 x 8 = 1024 blocks
    fused_kernel<<<grid, 256, 0, stream>>>(X, A, c0, out, sim);
}